// Round 1
// baseline (296.080 us; speedup 1.0000x reference)
//
#include <hip/hip_runtime.h>

// Problem constants (from reference): B=8, C=64, H=256, W=256
#define BB 8
#define CC 64
#define HH 256
#define WW 256
#define HW (HH*WW)

__device__ __forceinline__ int reflect_idx(int v, int n) {
    // jnp.pad mode='reflect': -1 -> 1, n -> n-2
    if (v < 0) v = -v;
    if (v >= n) v = 2*n - 2 - v;
    return v;
}

__global__ __launch_bounds__(256, 3)
void corr_fused_kernel(const float* __restrict__ hs,
                       const float* __restrict__ refLR,
                       const float* __restrict__ w_first,
                       const float* __restrict__ b_first,
                       const float* __restrict__ w_fuse,
                       const float* __restrict__ b_fuse,
                       float* __restrict__ out) {
    // LDS: transposed fuse weights [k][o] (32 KB) + one 16-channel ref halo chunk (20.7 KB)
    __shared__ float s_wT[128*64];
    __shared__ float s_ref[16*324];

    const int t  = threadIdx.x;
    const int tx = t & 15;
    const int ty = t >> 4;
    const int bx = blockIdx.x;   // W tile
    const int by = blockIdx.y;   // H tile
    const int b  = blockIdx.z;   // batch

    // ---- Phase 0a: transpose w_fuse[o][k] -> s_wT[k*64+o] (coalesced read) ----
    #pragma unroll
    for (int i = 0; i < 32; ++i) {
        int idx = t + i*256;          // 0..8191
        int o = idx >> 7;
        int k = idx & 127;
        s_wT[k*64 + o] = w_fuse[idx];
    }

    // ---- Phase 0b: load ref_LR halo inputs into registers (2 positions/thread) ----
    // halo is 18x18 = 324 positions for a 16x16 tile
    float rin0[9], rin1[9];
    {
        int py = t / 18, px = t % 18;
        int gy = reflect_idx(by*16 + py - 1, HH);
        int gx = reflect_idx(bx*16 + px - 1, WW);
        const float* rp = refLR + (size_t)b*9*HW + gy*WW + gx;
        #pragma unroll
        for (int j = 0; j < 9; ++j) rin0[j] = rp[(size_t)j*HW];
    }
    const int pos1 = t + 256;
    if (pos1 < 324) {
        int py = pos1 / 18, px = pos1 % 18;
        int gy = reflect_idx(by*16 + py - 1, HH);
        int gx = reflect_idx(bx*16 + px - 1, WW);
        const float* rp = refLR + (size_t)b*9*HW + gy*WW + gx;
        #pragma unroll
        for (int j = 0; j < 9; ++j) rin1[j] = rp[(size_t)j*HW];
    } else {
        #pragma unroll
        for (int j = 0; j < 9; ++j) rin1[j] = 0.f;
    }

    // ---- per-pixel neighbor offsets (reflect only matters at image edge) ----
    const int y = by*16 + ty;
    const int x = bx*16 + tx;
    const int ym = reflect_idx(y-1, HH), yp = reflect_idx(y+1, HH);
    const int xm = reflect_idx(x-1, WW), xp = reflect_idx(x+1, WW);
    int off[9];
    off[0]=ym*WW+xm; off[1]=ym*WW+x; off[2]=ym*WW+xp;
    off[3]= y*WW+xm; off[4]= y*WW+x; off[5]= y*WW+xp;
    off[6]=yp*WW+xm; off[7]=yp*WW+x; off[8]=yp*WW+xp;
    // LDS halo offsets for this pixel (halo coords: pixel (ty,tx) -> halo (ty+1,tx+1))
    int roff[9];
    #pragma unroll
    for (int dy = 0; dy < 3; ++dy)
        #pragma unroll
        for (int dx = 0; dx < 3; ++dx)
            roff[dy*3+dx] = (ty+dy)*18 + (tx+dx);

    // ---- accumulators ----
    float acc[64];
    #pragma unroll
    for (int o = 0; o < 64; ++o) acc[o] = b_fuse[o];

    // ---- main loop over 4 channel chunks of 16 ----
    #pragma unroll 1
    for (int ch = 0; ch < 4; ++ch) {
        __syncthreads();   // protect s_ref reuse (and covers s_wT on first iter)

        // Phase 1: compute ref chunk (16 channels) into LDS from register rin
        #pragma unroll 1
        for (int cc = 0; cc < 16; ++cc) {
            int c = ch*16 + cc;
            float v0 = b_first[c];
            float v1 = v0;
            #pragma unroll
            for (int j = 0; j < 9; ++j) {
                float w = w_first[c*9 + j];
                v0 += w * rin0[j];
                v1 += w * rin1[j];
            }
            v0 = v0 > 0.f ? v0 : 0.1f*v0;
            v1 = v1 > 0.f ? v1 : 0.1f*v1;
            s_ref[cc*324 + t] = v0;
            if (pos1 < 324) s_ref[cc*324 + pos1] = v1;
        }
        __syncthreads();

        // Phase 2: per channel: cross-corr 3x3, sigmoid gate, conv accumulation
        #pragma unroll 1
        for (int cc = 0; cc < 16; ++cc) {
            const int c = ch*16 + cc;
            const float* hp = hs + (size_t)(b*CC + c)*HW;   // wave-uniform base
            float h[9];
            #pragma unroll
            for (int j = 0; j < 9; ++j) h[j] = hp[off[j]];
            const float* rr = &s_ref[cc*324];
            float cross = 0.f;
            #pragma unroll
            for (int j = 0; j < 9; ++j) cross += h[j] * rr[roff[j]];
            // sigmoid(cross) = 1 / (1 + 2^(-cross*log2 e))
            float att = __builtin_amdgcn_rcpf(
                1.0f + __builtin_amdgcn_exp2f(cross * -1.44269504088896f));
            const float a  = att * h[4];
            const float hv = h[4];
            const float* wa = &s_wT[c*64];        // uniform-address broadcast reads
            const float* wb = &s_wT[(64 + c)*64];
            #pragma unroll
            for (int o = 0; o < 64; ++o)
                acc[o] += wa[o]*a + wb[o]*hv;
        }
    }

    // ---- epilogue: write out[b][o][y][x] ----
    float* op = out + (size_t)b*CC*HW + y*WW + x;
    #pragma unroll
    for (int o = 0; o < 64; ++o) op[(size_t)o*HW] = acc[o];
}

extern "C" void kernel_launch(void* const* d_in, const int* in_sizes, int n_in,
                              void* d_out, int out_size, void* d_ws, size_t ws_size,
                              hipStream_t stream) {
    const float* hs      = (const float*)d_in[0];
    const float* refLR   = (const float*)d_in[1];
    const float* w_first = (const float*)d_in[2];
    const float* b_first = (const float*)d_in[3];
    const float* w_fuse  = (const float*)d_in[4];
    const float* b_fuse  = (const float*)d_in[5];
    float* out = (float*)d_out;

    dim3 grid(WW/16, HH/16, BB);
    dim3 block(256);
    corr_fused_kernel<<<grid, block, 0, stream>>>(hs, refLR, w_first, b_first,
                                                  w_fuse, b_fuse, out);
}

// Round 2
// 161.126 us; speedup vs baseline: 1.8376x; 1.8376x over previous
//
#include <hip/hip_runtime.h>

// B=8, C=64, H=256, W=256
#define BB 8
#define CC 64
#define HH 256
#define WW 256
#define HW (HH*WW)

typedef __attribute__((ext_vector_type(8))) short bf16x8;
typedef __attribute__((ext_vector_type(4))) float f32x4;
typedef __attribute__((ext_vector_type(2))) float f32x2;

__device__ __forceinline__ int reflect_idx(int v, int n) {
    // jnp.pad mode='reflect': -1 -> 1, n -> n-2
    if (v < 0) v = -v;
    if (v >= n) v = 2*n - 2 - v;
    return v;
}

// f32 -> bf16 (round-to-nearest-even), as raw bits in a short
__device__ __forceinline__ short f2bf(float f) {
    union { float f; unsigned u; } x; x.f = f;
    unsigned r = (x.u + 0x7fffu + ((x.u >> 16) & 1u)) >> 16;
    return (short)r;
}

__global__ __launch_bounds__(256, 2)
void corr_mfma_kernel(const float* __restrict__ hs,
                      const float* __restrict__ refLR,
                      const float* __restrict__ w_first,
                      const float* __restrict__ b_first,
                      const float* __restrict__ w_fuse,
                      const float* __restrict__ b_fuse,
                      float* __restrict__ out) {
    // fused activations [pix 0..255][k 0..127], padded row to 136 bf16 (272B, 16B-aligned rows)
    __shared__ short s_fused[256 * 136];          // 69632 B
    __shared__ float s_p[324 * 4];                // p = hs*ref, 4-ch chunk   5184 B
    __shared__ float s_hs[324 * 4];               // hs halo, 4-ch chunk      5184 B
                                                  // total = 80000 B -> 2 blocks/CU

    const int t    = threadIdx.x;
    const int tx   = t & 15, ty = t >> 4;
    const int bx   = blockIdx.x, by = blockIdx.y, b = blockIdx.z;
    const int wave = t >> 6,  lane = t & 63;

    // ---- A-fragments (w_fuse rows for this wave's 16 out-channels), f32->bf16 in regs ----
    bf16x8 afrag[4];
    {
        const int m  = wave * 16 + (lane & 15);
        const int kb = lane >> 4;                 // k-subblock 0..3
        #pragma unroll
        for (int ks = 0; ks < 4; ++ks) {
            const float* wp = w_fuse + m * 128 + ks * 32 + kb * 8;
            bf16x8 f;
            #pragma unroll
            for (int j = 0; j < 8; ++j) f[j] = f2bf(wp[j]);
            afrag[ks] = f;
        }
    }
    // bias folded into accumulator init: C/D row = wave*16 + (lane>>4)*4 + r
    f32x4 acc_init;
    {
        const int o0 = wave * 16 + (lane >> 4) * 4;
        #pragma unroll
        for (int r = 0; r < 4; ++r) acc_init[r] = b_fuse[o0 + r];
    }

    // ---- halo setup: 18x18 = 324 positions; thread owns pos t (and t+256 if <324) ----
    float rin0[9], rin1[9];
    int g0 = 0, g1 = 0;
    {
        const int py = t / 18, px = t % 18;
        const int gy = reflect_idx(by * 16 + py - 1, HH);
        const int gx = reflect_idx(bx * 16 + px - 1, WW);
        g0 = gy * WW + gx;
        const float* rp = refLR + (size_t)b * 9 * HW + g0;
        #pragma unroll
        for (int j = 0; j < 9; ++j) rin0[j] = rp[(size_t)j * HW];
    }
    const bool has1 = (t + 256) < 324;
    if (has1) {
        const int pos = t + 256;
        const int py = pos / 18, px = pos % 18;
        const int gy = reflect_idx(by * 16 + py - 1, HH);
        const int gx = reflect_idx(bx * 16 + px - 1, WW);
        g1 = gy * WW + gx;
        const float* rp = refLR + (size_t)b * 9 * HW + g1;
        #pragma unroll
        for (int j = 0; j < 9; ++j) rin1[j] = rp[(size_t)j * HW];
    } else {
        #pragma unroll
        for (int j = 0; j < 9; ++j) rin1[j] = 0.f;
    }

    // per-pixel window offsets into the 18x18 halo
    int roff[9];
    #pragma unroll
    for (int dy = 0; dy < 3; ++dy)
        #pragma unroll
        for (int dx = 0; dx < 3; ++dx)
            roff[dy * 3 + dx] = (ty + dy) * 18 + (tx + dx);

    const float* hsb = hs + (size_t)b * CC * HW;

    // ---- main loop: 16 chunks of 4 channels ----
    #pragma unroll 1
    for (int ch = 0; ch < 16; ++ch) {
        const int c0 = ch * 4;
        __syncthreads();   // s_p/s_hs safe to overwrite

        // halo phase: ref conv (from rin regs) + hs load -> p, hs into LDS
        f32x4 p0, h0, p1, h1;
        #pragma unroll
        for (int cc = 0; cc < 4; ++cc) {
            const int c = c0 + cc;
            float v0 = b_first[c], v1 = v0;
            #pragma unroll
            for (int j = 0; j < 9; ++j) {
                const float w = w_first[c * 9 + j];
                v0 = fmaf(w, rin0[j], v0);
                v1 = fmaf(w, rin1[j], v1);
            }
            v0 = v0 > 0.f ? v0 : 0.1f * v0;
            v1 = v1 > 0.f ? v1 : 0.1f * v1;
            const float hv0 = hsb[(size_t)c * HW + g0];
            h0[cc] = hv0; p0[cc] = hv0 * v0;
            if (has1) {
                const float hv1 = hsb[(size_t)c * HW + g1];
                h1[cc] = hv1; p1[cc] = hv1 * v1;
            }
        }
        *(f32x4*)&s_p[t * 4]  = p0;
        *(f32x4*)&s_hs[t * 4] = h0;
        if (has1) {
            *(f32x4*)&s_p[(t + 256) * 4]  = p1;
            *(f32x4*)&s_hs[(t + 256) * 4] = h1;
        }
        __syncthreads();

        // pixel phase: 3x3 box-sum of p -> sigmoid -> fused bf16 into LDS
        f32x2 cr01 = {0.f, 0.f}, cr23 = {0.f, 0.f};
        #pragma unroll
        for (int j = 0; j < 9; ++j) {
            cr01 += *(const f32x2*)&s_p[roff[j] * 4];
            cr23 += *(const f32x2*)&s_p[roff[j] * 4 + 2];
        }
        const f32x2 hc01 = *(const f32x2*)&s_hs[roff[4] * 4];
        const f32x2 hc23 = *(const f32x2*)&s_hs[roff[4] * 4 + 2];
        const float cross[4] = {cr01[0], cr01[1], cr23[0], cr23[1]};
        const float hc[4]    = {hc01[0], hc01[1], hc23[0], hc23[1]};

        union { short s[4]; int2 v; } pa, ph;
        #pragma unroll
        for (int cc = 0; cc < 4; ++cc) {
            const float att = __builtin_amdgcn_rcpf(
                1.0f + __builtin_amdgcn_exp2f(cross[cc] * -1.44269504088896f));
            pa.s[cc] = f2bf(att * hc[cc]);
            ph.s[cc] = f2bf(hc[cc]);
        }
        *(int2*)&s_fused[t * 136 + c0]      = pa.v;   // k = c0..c0+3      (att*hs)
        *(int2*)&s_fused[t * 136 + 64 + c0] = ph.v;   // k = 64+c0..       (hs)
    }

    __syncthreads();

    // ---- MFMA phase: out[64][256pix] = W[64][128] x fused[128][256] ----
    const int px = lane & 15;
    const int kb = lane >> 4;
    float* op0 = out + ((size_t)b * CC + wave * 16 + kb * 4) * HW
                     + (size_t)(by * 16) * WW + bx * 16 + px;
    #pragma unroll 1
    for (int nt = 0; nt < 16; ++nt) {
        const short* bp = &s_fused[(nt * 16 + px) * 136 + kb * 8];
        f32x4 acc = acc_init;
        #pragma unroll
        for (int ks = 0; ks < 4; ++ks) {
            const bf16x8 bfrag = *(const bf16x8*)(bp + ks * 32);
            acc = __builtin_amdgcn_mfma_f32_16x16x32_bf16(afrag[ks], bfrag, acc, 0, 0, 0);
        }
        float* op = op0 + nt * WW;   // N-tile nt == image row by*16+nt
        #pragma unroll
        for (int r = 0; r < 4; ++r) op[(size_t)r * HW] = acc[r];
    }
}

extern "C" void kernel_launch(void* const* d_in, const int* in_sizes, int n_in,
                              void* d_out, int out_size, void* d_ws, size_t ws_size,
                              hipStream_t stream) {
    const float* hs      = (const float*)d_in[0];
    const float* refLR   = (const float*)d_in[1];
    const float* w_first = (const float*)d_in[2];
    const float* b_first = (const float*)d_in[3];
    const float* w_fuse  = (const float*)d_in[4];
    const float* b_fuse  = (const float*)d_in[5];
    float* out = (float*)d_out;

    dim3 grid(WW / 16, HH / 16, BB);
    dim3 block(256);
    corr_mfma_kernel<<<grid, block, 0, stream>>>(hs, refLR, w_first, b_first,
                                                 w_fuse, b_fuse, out);
}

// Round 3
// 122.198 us; speedup vs baseline: 2.4230x; 1.3186x over previous
//
#include <hip/hip_runtime.h>

// B=8, C=64, H=256, W=256
#define BB 8
#define CC 64
#define HH 256
#define WW 256
#define HW (HH*WW)

typedef __attribute__((ext_vector_type(8))) short bf16x8;
typedef __attribute__((ext_vector_type(4))) float f32x4;
typedef __attribute__((ext_vector_type(2))) float f32x2;

__device__ __forceinline__ int reflect_idx(int v, int n) {
    // jnp.pad mode='reflect': -1 -> 1, n -> n-2
    if (v < 0) v = -v;
    if (v >= n) v = 2*n - 2 - v;
    return v;
}

// f32 -> bf16 (RNE) raw bits
__device__ __forceinline__ short f2bf(float f) {
    union { float f; unsigned u; } x; x.f = f;
    unsigned r = (x.u + 0x7fffu + ((x.u >> 16) & 1u)) >> 16;
    return (short)r;
}

__device__ __forceinline__ unsigned cvt_pk_bf16(float lo, float hi) {
    unsigned r;
    asm("v_cvt_pk_bf16_f32 %0, %1, %2" : "=v"(r) : "v"(lo), "v"(hi));
    return r;
}

__global__ __launch_bounds__(256, 3)
void corr_wave_kernel(const float* __restrict__ hs,
                      const float* __restrict__ refLR,
                      const float* __restrict__ w_first,
                      const float* __restrict__ b_first,
                      const float* __restrict__ w_fuse,
                      const float* __restrict__ b_fuse,
                      float* __restrict__ out) {
    // s_w: reordered bf16 w_fuse [o 64][k' 128 pad 136]; k' = g*32+i,
    //      i<16 -> att weight col g*16+i, i>=16 -> hs weight col 64+g*16+(i-16)
    __shared__ short s_w[64 * 136];            // 17408 B (block-shared, read-only)
    __shared__ short s_fused[4][64 * 40];      // 20480 B (per-wave [pix 64][k 32 pad 40])
    __shared__ float s_p01[4][200];            // per-wave p=hs*ref ch0,1 at 100 halo pos
    __shared__ float s_p23[4][200];            // ch2,3
                                               // total 44288 B -> 3 blocks/CU

    const int t = threadIdx.x;
    const int wv = t >> 6, lane = t & 63;

    // XCD swizzle: each XCD (d%8) owns one batch image; raster order inside
    const int d = (int)blockIdx.x;
    const int lid = (d & 7) * 256 + (d >> 3);
    const int bx = lid & 15, by = (lid >> 4) & 15, b = lid >> 8;

    // ---- one-time: stage reordered bf16 weights ----
    #pragma unroll
    for (int r = 0; r < 32; ++r) {
        int idx = t + r * 256;              // = m*128 + k'
        int m = idx >> 7, kp = idx & 127;
        int g = kp >> 5, i = kp & 31;
        int src = (i < 16) ? (g * 16 + i) : (48 + g * 16 + i);
        s_w[m * 136 + kp] = f2bf(w_fuse[m * 128 + src]);
    }
    __syncthreads();   // the only block barrier

    // ---- wave tile: 8x8 pixels; block tile 16x16 (2x2 waves) ----
    const int wy = (wv >> 1) * 8, wx = (wv & 1) * 8;
    const int y0 = by * 16 + wy, x0 = bx * 16 + wx;

    // halo: 10x10 = 100 positions; lane owns pos=lane (+ pos=64+lane if lane<36)
    const bool has1 = lane < 36;
    int g0, g1;
    {
        const int py = lane / 10, px = lane % 10;
        g0 = reflect_idx(y0 + py - 1, HH) * WW + reflect_idx(x0 + px - 1, WW);
    }
    {
        const int pp = 64 + lane;
        const int py = pp / 10, px = pp % 10;
        g1 = has1 ? (reflect_idx(y0 + py - 1, HH) * WW + reflect_idx(x0 + px - 1, WW)) : g0;
    }
    const int pyc = lane >> 3, pxc = lane & 7;       // this lane's pixel
    const int gc = (y0 + pyc) * WW + (x0 + pxc);

    // refLR halo values in registers
    const float* rb = refLR + (size_t)b * 9 * HW;
    float rin0[9], rin1[9];
    #pragma unroll
    for (int j = 0; j < 9; ++j) rin0[j] = rb[(size_t)j * HW + g0];
    #pragma unroll
    for (int j = 0; j < 9; ++j) rin1[j] = rb[(size_t)j * HW + g1];

    // accumulators (bias-initialized). C/D: col=lane&15, row=(lane>>4)*4+r
    const int cl = lane & 15, kb = lane >> 4;
    f32x4 acc[4][4];
    #pragma unroll
    for (int mt = 0; mt < 4; ++mt) {
        #pragma unroll
        for (int r = 0; r < 4; ++r) {
            const float bv = b_fuse[mt * 16 + kb * 4 + r];
            #pragma unroll
            for (int nt = 0; nt < 4; ++nt) acc[mt][nt][r] = bv;
        }
    }

    const float* hsb = hs + (size_t)b * CC * HW;
    float* const sp01 = s_p01[wv];
    float* const sp23 = s_p23[wv];
    short* const sfw  = s_fused[wv];
    const int pb = (pyc * 10 + pxc) * 2;   // box-window base (float index)

    // prefetch chunk 0 hs values
    float h0[4], h1[4], hc[4];
    #pragma unroll
    for (int cc = 0; cc < 4; ++cc) {
        const float* hp = hsb + (size_t)cc * HW;
        h0[cc] = hp[g0]; h1[cc] = hp[g1]; hc[cc] = hp[gc];
    }

    #pragma unroll 1
    for (int ch = 0; ch < 16; ++ch) {
        const int c0 = ch * 4;

        // ref 1x1 conv + leaky + p-products for this lane's halo positions
        float pr0[4], pr1[4], hcv[4];
        #pragma unroll
        for (int cc = 0; cc < 4; ++cc) {
            const int c = c0 + cc;
            float v0 = b_first[c], v1 = v0;
            #pragma unroll
            for (int j = 0; j < 9; ++j) {
                const float w = w_first[c * 9 + j];   // wave-uniform (s_load)
                v0 = fmaf(w, rin0[j], v0);
                v1 = fmaf(w, rin1[j], v1);
            }
            v0 = v0 > 0.f ? v0 : 0.1f * v0;
            v1 = v1 > 0.f ? v1 : 0.1f * v1;
            pr0[cc] = h0[cc] * v0;
            pr1[cc] = h1[cc] * v1;
            hcv[cc] = hc[cc];
        }
        *(f32x2*)&sp01[lane * 2] = (f32x2){pr0[0], pr0[1]};
        *(f32x2*)&sp23[lane * 2] = (f32x2){pr0[2], pr0[3]};
        if (has1) {
            *(f32x2*)&sp01[(64 + lane) * 2] = (f32x2){pr1[0], pr1[1]};
            *(f32x2*)&sp23[(64 + lane) * 2] = (f32x2){pr1[2], pr1[3]};
        }
        // wave-local LDS RAW fence (no s_barrier needed: data is wave-private)
        asm volatile("s_waitcnt lgkmcnt(0)" ::: "memory");

        // 3x3 box-sum of p
        f32x2 a01 = (f32x2){0.f, 0.f}, a23 = (f32x2){0.f, 0.f};
        #pragma unroll
        for (int dy = 0; dy < 3; ++dy)
            #pragma unroll
            for (int dx = 0; dx < 3; ++dx) {
                const int o = pb + (dy * 10 + dx) * 2;
                a01 += *(const f32x2*)&sp01[o];
                a23 += *(const f32x2*)&sp23[o];
            }

        // issue next chunk's hs loads now (hidden under sigmoid/MFMA/next conv)
        {
            const int cn = ((ch + 1) & 15) * 4;
            #pragma unroll
            for (int cc = 0; cc < 4; ++cc) {
                const float* hp = hsb + (size_t)(cn + cc) * HW;
                h0[cc] = hp[g0]; h1[cc] = hp[g1]; hc[cc] = hp[gc];
            }
        }

        // sigmoid gate, bf16 pack, write k-slice of fused
        const float cr[4] = {a01[0], a01[1], a23[0], a23[1]};
        float av[4];
        #pragma unroll
        for (int cc = 0; cc < 4; ++cc)
            av[cc] = __builtin_amdgcn_rcpf(
                1.0f + __builtin_amdgcn_exp2f(cr[cc] * -1.44269504088896f)) * hcv[cc];
        uint2 ua, uh;
        ua.x = cvt_pk_bf16(av[0], av[1]);
        ua.y = cvt_pk_bf16(av[2], av[3]);
        uh.x = cvt_pk_bf16(hcv[0], hcv[1]);
        uh.y = cvt_pk_bf16(hcv[2], hcv[3]);
        const int k4 = (ch & 3) * 4;
        *(uint2*)&sfw[lane * 40 + k4] = ua;        // att*hs at k = k4..k4+3
        *(uint2*)&sfw[lane * 40 + 16 + k4] = uh;   // hs     at k = 16+k4..

        // group boundary: one k=32 MFMA slice, accumulate
        if ((ch & 3) == 3) {
            asm volatile("s_waitcnt lgkmcnt(0)" ::: "memory");
            const int g = ch >> 2;
            #pragma unroll
            for (int nt = 0; nt < 4; ++nt) {
                const bf16x8 bf = *(const bf16x8*)&sfw[(nt * 16 + cl) * 40 + kb * 8];
                #pragma unroll
                for (int mt = 0; mt < 4; ++mt) {
                    const bf16x8 af = *(const bf16x8*)&s_w[(mt * 16 + cl) * 136 + g * 32 + kb * 8];
                    acc[mt][nt] = __builtin_amdgcn_mfma_f32_16x16x32_bf16(af, bf, acc[mt][nt], 0, 0, 0);
                }
            }
        }
    }

    // ---- epilogue: store ----
    float* const ob = out + (size_t)b * CC * HW;
    #pragma unroll
    for (int mt = 0; mt < 4; ++mt) {
        const int o0 = mt * 16 + kb * 4;
        #pragma unroll
        for (int nt = 0; nt < 4; ++nt) {
            const int p = nt * 16 + cl;           // pixel index in 8x8 tile
            float* op = ob + (size_t)o0 * HW + (size_t)(y0 + (p >> 3)) * WW + (x0 + (p & 7));
            #pragma unroll
            for (int r = 0; r < 4; ++r) op[(size_t)r * HW] = acc[mt][nt][r];
        }
    }
}

extern "C" void kernel_launch(void* const* d_in, const int* in_sizes, int n_in,
                              void* d_out, int out_size, void* d_ws, size_t ws_size,
                              hipStream_t stream) {
    const float* hs      = (const float*)d_in[0];
    const float* refLR   = (const float*)d_in[1];
    const float* w_first = (const float*)d_in[2];
    const float* b_first = (const float*)d_in[3];
    const float* w_fuse  = (const float*)d_in[4];
    const float* b_fuse  = (const float*)d_in[5];
    float* out = (float*)d_out;

    corr_wave_kernel<<<dim3(2048), dim3(256), 0, stream>>>(hs, refLR, w_first, b_first,
                                                           w_fuse, b_fuse, out);
}